// Round 13
// baseline (133.405 us; speedup 1.0000x reference)
//
#include <hip/hip_runtime.h>
#include <hip/hip_bf16.h>

#define HW 4096
#define CC 128
// softmax in exp2 domain: scale folded into q projection weights
#define SCALE_LOG2E (0.17677669529663687f * 1.4426950408889634f)
#define KSPLIT 8
#define H1PAD 4096  // shorts of padding each side of h1T (shift range +/-65 px)

typedef short bf16x8 __attribute__((ext_vector_type(8)));
typedef short bf16x4 __attribute__((ext_vector_type(4)));
typedef float f32x4 __attribute__((ext_vector_type(4)));

static __device__ __forceinline__ unsigned short f2bf(float f) {
  unsigned int u = __float_as_uint(f);
  unsigned int r = (u + 0x7fffu + ((u >> 16) & 1u)) >> 16;
  return (unsigned short)r;
}
// pack two f32 -> {bf16(lo), bf16(hi)} in ONE v_perm (truncating)
static __device__ __forceinline__ unsigned int pk2bf(float lo, float hi) {
  return __builtin_amdgcn_perm(__float_as_uint(hi), __float_as_uint(lo),
                               0x07060302u);
}
static __device__ __forceinline__ unsigned int pk2bf_rne(float lo, float hi) {
  return (unsigned int)f2bf(lo) | ((unsigned int)f2bf(hi) << 16);
}
static __device__ __forceinline__ f32x4 mfma16(bf16x8 a, bf16x8 b, f32x4 c) {
  return __builtin_amdgcn_mfma_f32_16x16x32_bf16(a, b, c, 0, 0, 0);
}
// K=16 bf16 MFMA (2-reg operands): B-layout matches S's C-layout exactly
// (verified on HW in r10/r11 runs).
static __device__ __forceinline__ f32x4 mfma16k16(bf16x4 a, bf16x4 b, f32x4 c) {
  return __builtin_amdgcn_mfma_f32_16x16x16bf16_1k(a, b, c, 0, 0, 0);
}
static __device__ __forceinline__ bf16x4 mkbf4(unsigned int lo, unsigned int hi) {
  uint2 u = {lo, hi};
  return *(bf16x4*)&u;
}

// ---------------------------------------------------------------------------
// prep: blocks 0..255 -> wcast (1x1 weights to bf16, Wq pre-scaled);
//       blocks 256..399 -> wcast2 (Wm2 -> [tap][co][ci] bf16);
//       blocks 400..431 -> conv1 3x3 1->32 + ReLU -> h1p [b][px][32] bf16.
__global__ __launch_bounds__(256) void prep_kernel(
    const float* __restrict__ Wq, const float* __restrict__ Wk,
    const float* __restrict__ Wv, const float* __restrict__ Wo,
    const float* __restrict__ Wm2, const float* __restrict__ seg,
    const float* __restrict__ Wm1, const float* __restrict__ bm1,
    unsigned short* __restrict__ wbf, unsigned short* __restrict__ wm2t,
    unsigned short* __restrict__ h1p) {
  __shared__ float wls[288];
  const int blk = blockIdx.x;
  const int t = threadIdx.x;
  if (blk < 256) {
    int i = blk * 256 + t;  // 0..65535
    int which = i >> 14, j = i & 16383;
    const float* src = which == 0 ? Wq : which == 1 ? Wk : which == 2 ? Wv : Wo;
    float v = src[j];
    if (which == 0) v *= SCALE_LOG2E;
    wbf[i] = f2bf(v);
  } else if (blk < 400) {
    int i = (blk - 256) * 256 + t;  // 0..36863
    int tap = i >> 12;
    int rem = i & 4095;
    int co = rem >> 5, ci = rem & 31;
    wm2t[i] = f2bf(Wm2[co * 288 + ci * 9 + tap]);
  } else {
    for (int j = t; j < 288; j += 256) wls[j] = Wm1[j];
    const int idx = (blk - 400) * 256 + t;  // 0..8191
    const int b = idx >> 12, p = idx & 4095;
    const int x = p & 63, y = p >> 6;
    const float* sb = seg + b * HW;
    float pix[9];
#pragma unroll
    for (int tap = 0; tap < 9; ++tap) {
      int dy = tap / 3 - 1, dx = tap % 3 - 1;
      int xx = x + dx, yy = y + dy;
      bool valid = ((unsigned)xx < 64u) & ((unsigned)yy < 64u);
      pix[tap] = valid ? sb[yy * 64 + xx] : 0.f;
    }
    __syncthreads();
    unsigned int pk[16];
#pragma unroll
    for (int cg = 0; cg < 16; ++cg) {
      float s0 = bm1[2 * cg], s1 = bm1[2 * cg + 1];
#pragma unroll
      for (int tap = 0; tap < 9; ++tap) {
        s0 += wls[(2 * cg) * 9 + tap] * pix[tap];
        s1 += wls[(2 * cg + 1) * 9 + tap] * pix[tap];
      }
      pk[cg] = pk2bf_rne(fmaxf(s0, 0.f), fmaxf(s1, 0.f));
    }
    unsigned short* dst = h1p + (size_t)idx * 32;
#pragma unroll
    for (int g = 0; g < 4; ++g) *(uint4*)(dst + g * 8) = *(uint4*)&pk[g * 4];
  }
}

// ---------------------------------------------------------------------------
// Fused conv2 (3x3 32->128, 9-tap shifted MFMA GEMM) + q/k/v 1x1 MFMA.
// 32-px blocks, grid (128, 2).  conv2 result stays in LDS (mT) and feeds
// k/v; sr staged (xT) feeds q.  (r9-proven structure, unchanged.)
__global__ __launch_bounds__(256) void conv2qkv_mfma(
    const float* __restrict__ sr, const unsigned short* __restrict__ h1p,
    const unsigned short* __restrict__ wm2t, const float* __restrict__ bm2,
    const unsigned short* __restrict__ wq, const float* __restrict__ bq,
    const unsigned short* __restrict__ wk, const float* __restrict__ bk,
    const unsigned short* __restrict__ wv, const float* __restrict__ bv,
    unsigned short* __restrict__ qt, unsigned short* __restrict__ kt,
    unsigned short* __restrict__ vt) {
  const int b   = blockIdx.y;
  const int px0 = blockIdx.x * 32;
  const int t   = threadIdx.x;
  const int w = t >> 6, lane = t & 63, col = lane & 15, quad = lane >> 4;

  __shared__ unsigned short mT[32][136];  // conv2 output (mask_feat) [px][ci]
  __shared__ unsigned short xT[32][136];  // sr [px][ci]

  // stage 0: sr -> LDS bf16 (q's B operand)
  for (int r = 0; r < 16; ++r) {
    int idx = r * 256 + t;
    int ci = idx >> 5, px = idx & 31;
    xT[px][ci] = f2bf(sr[((size_t)b * CC + ci) * HW + px0 + px]);
  }

  // stage 1: conv2 -> mT
  {
    bf16x8 afrag[9][2];
#pragma unroll
    for (int tap = 0; tap < 9; ++tap) {
      const unsigned short* wb =
          wm2t + ((size_t)tap * 128 + w * 32 + col) * 32 + quad * 8;
      afrag[tap][0] = *(const bf16x8*)wb;
      afrag[tap][1] = *(const bf16x8*)(wb + 16 * 32);
    }
    const unsigned short* xb = h1p + (size_t)b * HW * 32;
    f32x4 acc[2][2] = {};
    const bf16x8 zf = {0, 0, 0, 0, 0, 0, 0, 0};
    const int px[2] = {px0 + col, px0 + 16 + col};
    const int xx[2] = {px[0] & 63, px[1] & 63};
    const int yy[2] = {px[0] >> 6, px[1] >> 6};
#pragma unroll
    for (int tap = 0; tap < 9; ++tap) {
      const int dy = tap / 3 - 1, dx = tap % 3 - 1;
      const int shift = dy * 64 + dx;
#pragma unroll
      for (int pt = 0; pt < 2; ++pt) {
        bool valid =
            ((unsigned)(xx[pt] + dx) < 64u) & ((unsigned)(yy[pt] + dy) < 64u);
        bf16x8 bf = *(const bf16x8*)(xb + (size_t)(px[pt] + shift) * 32 + quad * 8);
        bf = valid ? bf : zf;
        acc[0][pt] = mfma16(afrag[tap][0], bf, acc[0][pt]);
        acc[1][pt] = mfma16(afrag[tap][1], bf, acc[1][pt]);
      }
    }
#pragma unroll
    for (int ct = 0; ct < 2; ++ct) {
      float4 bb = *(const float4*)(bm2 + w * 32 + ct * 16 + quad * 4);
#pragma unroll
      for (int pt = 0; pt < 2; ++pt) {
        uint2 pk = {pk2bf_rne(acc[ct][pt][0] + bb.x, acc[ct][pt][1] + bb.y),
                    pk2bf_rne(acc[ct][pt][2] + bb.z, acc[ct][pt][3] + bb.w)};
        *(uint2*)&mT[pt * 16 + col][w * 32 + ct * 16 + quad * 4] = pk;
      }
    }
  }
  __syncthreads();

  // stage 2: q (from xT), k/v (from mT) 1x1 GEMMs
  f32x4 aq[2][2] = {}, ak[2][2] = {}, av[2][2] = {};
  const unsigned short* wqb = wq + (size_t)(w * 32 + col) * CC + quad * 8;
  const unsigned short* wkb = wk + (size_t)(w * 32 + col) * CC + quad * 8;
  const unsigned short* wvb = wv + (size_t)(w * 32 + col) * CC + quad * 8;
#pragma unroll
  for (int ks = 0; ks < 4; ++ks) {
    bf16x8 qa0 = *(const bf16x8*)(wqb + ks * 32);
    bf16x8 qa1 = *(const bf16x8*)(wqb + 16 * CC + ks * 32);
    bf16x8 ka0 = *(const bf16x8*)(wkb + ks * 32);
    bf16x8 ka1 = *(const bf16x8*)(wkb + 16 * CC + ks * 32);
    bf16x8 va0 = *(const bf16x8*)(wvb + ks * 32);
    bf16x8 va1 = *(const bf16x8*)(wvb + 16 * CC + ks * 32);
    bf16x8 bx0 = *(const bf16x8*)&xT[col][ks * 32 + quad * 8];
    bf16x8 bx1 = *(const bf16x8*)&xT[16 + col][ks * 32 + quad * 8];
    bf16x8 bm0 = *(const bf16x8*)&mT[col][ks * 32 + quad * 8];
    bf16x8 bm1f = *(const bf16x8*)&mT[16 + col][ks * 32 + quad * 8];
    aq[0][0] = mfma16(qa0, bx0, aq[0][0]);
    aq[0][1] = mfma16(qa0, bx1, aq[0][1]);
    aq[1][0] = mfma16(qa1, bx0, aq[1][0]);
    aq[1][1] = mfma16(qa1, bx1, aq[1][1]);
    ak[0][0] = mfma16(ka0, bm0, ak[0][0]);
    ak[0][1] = mfma16(ka0, bm1f, ak[0][1]);
    ak[1][0] = mfma16(ka1, bm0, ak[1][0]);
    ak[1][1] = mfma16(ka1, bm1f, ak[1][1]);
    av[0][0] = mfma16(va0, bm0, av[0][0]);
    av[0][1] = mfma16(va0, bm1f, av[0][1]);
    av[1][0] = mfma16(va1, bm0, av[1][0]);
    av[1][1] = mfma16(va1, bm1f, av[1][1]);
  }
  const int bh = b * 4 + w;
  const int chunk = blockIdx.x;
#pragma unroll
  for (int ct = 0; ct < 2; ++ct) {
    float4 bbq = *(const float4*)(bq + w * 32 + ct * 16 + quad * 4);
    float4 bbk = *(const float4*)(bk + w * 32 + ct * 16 + quad * 4);
    float4 bbv = *(const float4*)(bv + w * 32 + ct * 16 + quad * 4);
#pragma unroll
    for (int pt = 0; pt < 2; ++pt) {
      int key = pt * 16 + col;  // pixel within this 32-px chunk
      // q (bias scaled like weights)
      uint2 pkq = {pk2bf_rne(aq[ct][pt][0] + bbq.x * SCALE_LOG2E,
                             aq[ct][pt][1] + bbq.y * SCALE_LOG2E),
                   pk2bf_rne(aq[ct][pt][2] + bbq.z * SCALE_LOG2E,
                             aq[ct][pt][3] + bbq.w * SCALE_LOG2E)};
      *(uint2*)(qt + ((size_t)bh * HW + px0 + key) * 32 + ct * 16 + quad * 4) = pkq;
      // k
      uint2 pkk = {pk2bf_rne(ak[ct][pt][0] + bbk.x, ak[ct][pt][1] + bbk.y),
                   pk2bf_rne(ak[ct][pt][2] + bbk.z, ak[ct][pt][3] + bbk.w)};
      *(uint2*)(kt + ((size_t)bh * HW + px0 + key) * 32 + ct * 16 + quad * 4) = pkk;
      // v: [bh][chunk][dim][key]
      unsigned short* vdst =
          vt + (((size_t)bh * 128 + chunk) * 32 + ct * 16 + quad * 4) * 32 + key;
      vdst[0]  = f2bf(av[ct][pt][0] + bbv.x);
      vdst[32] = f2bf(av[ct][pt][1] + bbv.y);
      vdst[64] = f2bf(av[ct][pt][2] + bbv.z);
      vdst[96] = f2bf(av[ct][pt][3] + bbv.w);
    }
  }
}

// ---------------------------------------------------------------------------
// Split-K flash attention, fixed m=0, 128 queries (8 Q-tiles) per wave:
// each K/V fragment pair feeds 8 S / 16 PV-K16 MFMAs -> half the fragment
// traffic of the 64q/wave version.  ZERO LDS (register PV via K=16 MFMA).
// Grid (8, 8, KSPLIT) x 256 threads; block: 512 queries x 512 keys.
__global__ __launch_bounds__(256, 2) void attn_mfma_kernel(
    const unsigned short* __restrict__ qt, const unsigned short* __restrict__ ktg,
    const unsigned short* __restrict__ vt, unsigned short* __restrict__ opart,
    float* __restrict__ lpart) {
  const int bh   = blockIdx.y;
  const int s    = blockIdx.z;
  const int t    = threadIdx.x;
  const int wave = t >> 6;
  const int lane = t & 63;
  const int col  = lane & 15;
  const int quad = lane >> 4;
  const int q0w  = blockIdx.x * 512 + wave * 128;

  const unsigned short* Qb = qt  + (size_t)bh * HW * 32;
  const unsigned short* Kb = ktg + (size_t)bh * HW * 32;
  const unsigned short* Vc = vt  + (size_t)bh * 128 * 1024;

  bf16x8 qf[8];
#pragma unroll
  for (int qt_i = 0; qt_i < 8; ++qt_i)
    qf[qt_i] = *(const bf16x8*)(Qb + (size_t)(q0w + qt_i * 16 + col) * 32 + quad * 8);

  float lacc[8] = {};
  f32x4 o[8][2] = {};
  const f32x4 zero = {0.f, 0.f, 0.f, 0.f};

  // K fragments (K=32 A-operand): lane col = key, quad*8 dims.
  const unsigned short* kp1 = Kb + (size_t)(s * 16) * 1024 + col * 32 + quad * 8;
  const unsigned short* kp2 = kp1 + 512;
  // V fragments (K=16 A-operand): lane col = dim, keys quad*4..+3 (b64).
  const unsigned short* vpa = Vc + (size_t)(s * 16) * 1024 + col * 32 + quad * 4;
  const unsigned short* vpb = vpa + 16;        // keys 16-31
  const unsigned short* vpc = vpa + 16 * 32;   // dims 16-31
  const unsigned short* vpd = vpc + 16;

  bf16x8 kf1 = *(const bf16x8*)(kp1);
  bf16x8 kf2 = *(const bf16x8*)(kp2);
  bf16x4 vfa = *(const bf16x4*)(vpa);
  bf16x4 vfb = *(const bf16x4*)(vpb);
  bf16x4 vfc = *(const bf16x4*)(vpc);
  bf16x4 vfd = *(const bf16x4*)(vpd);

  for (int c = 0; c < 16; ++c) {
    // prefetch next chunk (c=15 overreads 2KB into adjacent region, unused)
    bf16x8 nk1 = *(const bf16x8*)(kp1 + (c + 1) * 1024);
    bf16x8 nk2 = *(const bf16x8*)(kp2 + (c + 1) * 1024);
    bf16x4 nva = *(const bf16x4*)(vpa + (c + 1) * 1024);
    bf16x4 nvb = *(const bf16x4*)(vpb + (c + 1) * 1024);
    bf16x4 nvc = *(const bf16x4*)(vpc + (c + 1) * 1024);
    bf16x4 nvd = *(const bf16x4*)(vpd + (c + 1) * 1024);
#pragma unroll
    for (int qt_i = 0; qt_i < 8; ++qt_i) {
      f32x4 s1 = mfma16(kf1, qf[qt_i], zero);
      f32x4 s2 = mfma16(kf2, qf[qt_i], zero);
      float p0 = __builtin_amdgcn_exp2f(s1[0]);
      float p1 = __builtin_amdgcn_exp2f(s1[1]);
      float p2 = __builtin_amdgcn_exp2f(s1[2]);
      float p3 = __builtin_amdgcn_exp2f(s1[3]);
      float p4 = __builtin_amdgcn_exp2f(s2[0]);
      float p5 = __builtin_amdgcn_exp2f(s2[1]);
      float p6 = __builtin_amdgcn_exp2f(s2[2]);
      float p7 = __builtin_amdgcn_exp2f(s2[3]);
      lacc[qt_i] += ((p0 + p1) + (p2 + p3)) + ((p4 + p5) + (p6 + p7));

      // P stays in registers: keys quad*4+r (pf1), 16+quad*4+r (pf2).
      bf16x4 pf1 = mkbf4(pk2bf(p0, p1), pk2bf(p2, p3));
      bf16x4 pf2 = mkbf4(pk2bf(p4, p5), pk2bf(p6, p7));
      o[qt_i][0] = mfma16k16(vfa, pf1, o[qt_i][0]);
      o[qt_i][0] = mfma16k16(vfb, pf2, o[qt_i][0]);
      o[qt_i][1] = mfma16k16(vfc, pf1, o[qt_i][1]);
      o[qt_i][1] = mfma16k16(vfd, pf2, o[qt_i][1]);
    }
    kf1 = nk1; kf2 = nk2;
    vfa = nva; vfb = nvb; vfc = nvc; vfd = nvd;
  }

#pragma unroll
  for (int qt_i = 0; qt_i < 8; ++qt_i) {
    float l = lacc[qt_i];
    l += __shfl_xor(l, 16);
    l += __shfl_xor(l, 32);
    int qq = q0w + qt_i * 16 + col;
    size_t base = ((size_t)(s * 8 + bh) * HW + qq) * 32;
    uint2 w1 = {pk2bf_rne(o[qt_i][0][0], o[qt_i][0][1]),
                pk2bf_rne(o[qt_i][0][2], o[qt_i][0][3])};
    uint2 w2 = {pk2bf_rne(o[qt_i][1][0], o[qt_i][1][1]),
                pk2bf_rne(o[qt_i][1][2], o[qt_i][1][3])};
    *(uint2*)(opart + base + quad * 4)      = w1;
    *(uint2*)(opart + base + 16 + quad * 4) = w2;
    if (quad == 0) lpart[(size_t)(s * 8 + bh) * HW + qq] = l;
  }
}

// ---------------------------------------------------------------------------
// Fused combine (KSPLIT partials -> guided, LDS) + output 1x1 conv + bias +
// residual.  Block: 32 px, 256 threads.  Grid (128, 2).
__global__ __launch_bounds__(256) void combine_convo(
    const unsigned short* __restrict__ opart, const float* __restrict__ lpart,
    const unsigned short* __restrict__ wo, const float* __restrict__ bo,
    const float* __restrict__ sr, float* __restrict__ out) {
  const int b   = blockIdx.y;
  const int px0 = blockIdx.x * 32;
  const int t   = threadIdx.x;

  __shared__ unsigned short gT[32][136];  // guided [px][ci]

  // stage 1: combine splits for this block's 32 px into gT
  {
    const int px = t & 31, cs = t >> 5;  // cs 0..7 -> 16-ci slice
    const int q  = px0 + px;
    const int bh = b * 4 + (cs >> 1);
    const int d0 = (cs & 1) * 16;
    float lsum = 0.f;
#pragma unroll
    for (int s = 0; s < KSPLIT; ++s) lsum += lpart[(size_t)(s * 8 + bh) * HW + q];
    float inv = 1.f / lsum;
    float acc[16];
#pragma unroll
    for (int j = 0; j < 16; ++j) acc[j] = 0.f;
#pragma unroll
    for (int s = 0; s < KSPLIT; ++s) {
      const unsigned short* src =
          opart + ((size_t)(s * 8 + bh) * HW + q) * 32 + d0;
#pragma unroll
      for (int g = 0; g < 2; ++g) {
        uint4 raw = *(const uint4*)(src + g * 8);
        const unsigned int* u = (const unsigned int*)&raw;
#pragma unroll
        for (int h = 0; h < 4; ++h) {
          acc[g * 8 + 2 * h]     += __uint_as_float(u[h] << 16);
          acc[g * 8 + 2 * h + 1] += __uint_as_float(u[h] & 0xffff0000u);
        }
      }
    }
    unsigned int pk[8];
#pragma unroll
    for (int j = 0; j < 8; ++j)
      pk[j] = pk2bf_rne(acc[2 * j] * inv, acc[2 * j + 1] * inv);
    *(uint4*)&gT[px][cs * 16]     = *(uint4*)&pk[0];
    *(uint4*)&gT[px][cs * 16 + 8] = *(uint4*)&pk[4];
  }
  __syncthreads();

  // stage 2: 1x1 conv Wo + bias + residual
  const int w = t >> 6, lane = t & 63, col = lane & 15, quad = lane >> 4;
  f32x4 acc2[2][2] = {};
  const unsigned short* wbase = wo + (size_t)(w * 32 + col) * CC + quad * 8;
#pragma unroll
  for (int ks = 0; ks < 4; ++ks) {
    bf16x8 a0 = *(const bf16x8*)(wbase + ks * 32);
    bf16x8 a1 = *(const bf16x8*)(wbase + 16 * CC + ks * 32);
    bf16x8 b0 = *(const bf16x8*)&gT[col][ks * 32 + quad * 8];
    bf16x8 b1 = *(const bf16x8*)&gT[16 + col][ks * 32 + quad * 8];
    acc2[0][0] = mfma16(a0, b0, acc2[0][0]);
    acc2[0][1] = mfma16(a0, b1, acc2[0][1]);
    acc2[1][0] = mfma16(a1, b0, acc2[1][0]);
    acc2[1][1] = mfma16(a1, b1, acc2[1][1]);
  }
#pragma unroll
  for (int ct = 0; ct < 2; ++ct) {
    float4 bb = *(const float4*)(bo + w * 32 + ct * 16 + quad * 4);
    float bias[4] = {bb.x, bb.y, bb.z, bb.w};
#pragma unroll
    for (int pt = 0; pt < 2; ++pt) {
      int px = px0 + pt * 16 + col;
      int co = w * 32 + ct * 16 + quad * 4;
      const float* rb = sr + ((size_t)b * CC + co) * HW + px;
      float* ob = out + ((size_t)b * CC + co) * HW + px;
#pragma unroll
      for (int r = 0; r < 4; ++r)
        ob[(size_t)r * HW] = acc2[ct][pt][r] + bias[r] + rb[(size_t)r * HW];
    }
  }
}

// ---------------------------------------------------------------------------
extern "C" void kernel_launch(void* const* d_in, const int* in_sizes, int n_in,
                              void* d_out, int out_size, void* d_ws, size_t ws_size,
                              hipStream_t stream) {
  const float* sr  = (const float*)d_in[0];
  const float* seg = (const float*)d_in[1];
  const float* Wq  = (const float*)d_in[2];
  const float* bq  = (const float*)d_in[3];
  const float* Wm1 = (const float*)d_in[4];
  const float* bm1 = (const float*)d_in[5];
  const float* Wm2 = (const float*)d_in[6];
  const float* bm2 = (const float*)d_in[7];
  const float* Wk  = (const float*)d_in[8];
  const float* bk  = (const float*)d_in[9];
  const float* Wv  = (const float*)d_in[10];
  const float* bv  = (const float*)d_in[11];
  const float* Wo  = (const float*)d_in[12];
  const float* bo  = (const float*)d_in[13];
  float* out = (float*)d_out;

  unsigned short* h1T = (unsigned short*)d_ws;      // pad + 2*4096*32 + pad
  unsigned short* h1p = h1T + H1PAD;                // usable base
  unsigned short* qt  = h1T + H1PAD + 262144 + H1PAD;
  unsigned short* kt  = qt + 1048576;
  unsigned short* vt  = kt + 1048576;
  unsigned short* wbf = vt + 1048576;               // 4x 1x1 weights bf16
  unsigned short* wm2t = wbf + 65536;               // conv2 weights [tap][co][ci]
  unsigned short* opart = wm2t + 36864;             // 16 MB (KSPLIT=8)
  float* lpart = (float*)(opart + (size_t)KSPLIT * 8 * HW * 32);  // 1 MB

  const unsigned short* wq = wbf;
  const unsigned short* wk = wbf + 16384;
  const unsigned short* wv = wbf + 32768;
  const unsigned short* wo = wbf + 49152;

  prep_kernel<<<432, 256, 0, stream>>>(Wq, Wk, Wv, Wo, Wm2, seg, Wm1, bm1,
                                       wbf, wm2t, h1p);
  conv2qkv_mfma<<<dim3(128, 2), 256, 0, stream>>>(
      sr, h1p, wm2t, bm2, wq, bq, wk, bk, wv, bv, qt, kt, vt);
  attn_mfma_kernel<<<dim3(8, 8, KSPLIT), 256, 0, stream>>>(qt, kt, vt, opart,
                                                           lpart);
  combine_convo<<<dim3(128, 2), 256, 0, stream>>>(opart, lpart, wo, bo, sr, out);
}

// Round 14
// 131.861 us; speedup vs baseline: 1.0117x; 1.0117x over previous
//
#include <hip/hip_runtime.h>
#include <hip/hip_bf16.h>

#define HW 4096
#define CC 128
// softmax in exp2 domain: scale folded into q projection weights
#define SCALE_LOG2E (0.17677669529663687f * 1.4426950408889634f)
#define KSPLIT 8
#define H1PAD 4096  // shorts of padding each side of h1T (shift range +/-65 px)

typedef short bf16x8 __attribute__((ext_vector_type(8)));
typedef float f32x4 __attribute__((ext_vector_type(4)));

static __device__ __forceinline__ unsigned short f2bf(float f) {
  unsigned int u = __float_as_uint(f);
  unsigned int r = (u + 0x7fffu + ((u >> 16) & 1u)) >> 16;
  return (unsigned short)r;
}
// pack two f32 -> {bf16(lo), bf16(hi)} in ONE v_perm (truncating)
static __device__ __forceinline__ unsigned int pk2bf(float lo, float hi) {
  return __builtin_amdgcn_perm(__float_as_uint(hi), __float_as_uint(lo),
                               0x07060302u);
}
static __device__ __forceinline__ unsigned int pk2bf_rne(float lo, float hi) {
  return (unsigned int)f2bf(lo) | ((unsigned int)f2bf(hi) << 16);
}
static __device__ __forceinline__ f32x4 mfma16(bf16x8 a, bf16x8 b, f32x4 c) {
  return __builtin_amdgcn_mfma_f32_16x16x32_bf16(a, b, c, 0, 0, 0);
}

// ---------------------------------------------------------------------------
// prep: blocks 0..255 -> wcast (1x1 weights to bf16, Wq pre-scaled);
//       blocks 256..399 -> wcast2 (Wm2 -> [tap][co][ci] bf16);
//       blocks 400..431 -> conv1 3x3 1->32 + ReLU -> h1p [b][px][32] bf16.
__global__ __launch_bounds__(256) void prep_kernel(
    const float* __restrict__ Wq, const float* __restrict__ Wk,
    const float* __restrict__ Wv, const float* __restrict__ Wo,
    const float* __restrict__ Wm2, const float* __restrict__ seg,
    const float* __restrict__ Wm1, const float* __restrict__ bm1,
    unsigned short* __restrict__ wbf, unsigned short* __restrict__ wm2t,
    unsigned short* __restrict__ h1p) {
  __shared__ float wls[288];
  const int blk = blockIdx.x;
  const int t = threadIdx.x;
  if (blk < 256) {
    int i = blk * 256 + t;  // 0..65535
    int which = i >> 14, j = i & 16383;
    const float* src = which == 0 ? Wq : which == 1 ? Wk : which == 2 ? Wv : Wo;
    float v = src[j];
    if (which == 0) v *= SCALE_LOG2E;
    wbf[i] = f2bf(v);
  } else if (blk < 400) {
    int i = (blk - 256) * 256 + t;  // 0..36863
    int tap = i >> 12;
    int rem = i & 4095;
    int co = rem >> 5, ci = rem & 31;
    wm2t[i] = f2bf(Wm2[co * 288 + ci * 9 + tap]);
  } else {
    for (int j = t; j < 288; j += 256) wls[j] = Wm1[j];
    const int idx = (blk - 400) * 256 + t;  // 0..8191
    const int b = idx >> 12, p = idx & 4095;
    const int x = p & 63, y = p >> 6;
    const float* sb = seg + b * HW;
    float pix[9];
#pragma unroll
    for (int tap = 0; tap < 9; ++tap) {
      int dy = tap / 3 - 1, dx = tap % 3 - 1;
      int xx = x + dx, yy = y + dy;
      bool valid = ((unsigned)xx < 64u) & ((unsigned)yy < 64u);
      pix[tap] = valid ? sb[yy * 64 + xx] : 0.f;
    }
    __syncthreads();
    unsigned int pk[16];
#pragma unroll
    for (int cg = 0; cg < 16; ++cg) {
      float s0 = bm1[2 * cg], s1 = bm1[2 * cg + 1];
#pragma unroll
      for (int tap = 0; tap < 9; ++tap) {
        s0 += wls[(2 * cg) * 9 + tap] * pix[tap];
        s1 += wls[(2 * cg + 1) * 9 + tap] * pix[tap];
      }
      pk[cg] = pk2bf_rne(fmaxf(s0, 0.f), fmaxf(s1, 0.f));
    }
    unsigned short* dst = h1p + (size_t)idx * 32;
#pragma unroll
    for (int g = 0; g < 4; ++g) *(uint4*)(dst + g * 8) = *(uint4*)&pk[g * 4];
  }
}

// ---------------------------------------------------------------------------
// Fused conv2 (3x3 32->128, 9-tap shifted MFMA GEMM) + q/k/v 1x1 MFMA.
// 32-px blocks, grid (128, 2).  conv2 result stays in LDS (mT) and feeds
// k/v; sr staged (xT) feeds q.
// Outputs: qt/kt bf16 [bh][px][32]; vt bf16 [bh][chunk][dim][key].
__global__ __launch_bounds__(256) void conv2qkv_mfma(
    const float* __restrict__ sr, const unsigned short* __restrict__ h1p,
    const unsigned short* __restrict__ wm2t, const float* __restrict__ bm2,
    const unsigned short* __restrict__ wq, const float* __restrict__ bq,
    const unsigned short* __restrict__ wk, const float* __restrict__ bk,
    const unsigned short* __restrict__ wv, const float* __restrict__ bv,
    unsigned short* __restrict__ qt, unsigned short* __restrict__ kt,
    unsigned short* __restrict__ vt) {
  const int b   = blockIdx.y;
  const int px0 = blockIdx.x * 32;
  const int t   = threadIdx.x;
  const int w = t >> 6, lane = t & 63, col = lane & 15, quad = lane >> 4;

  __shared__ unsigned short mT[32][136];  // conv2 output (mask_feat) [px][ci]
  __shared__ unsigned short xT[32][136];  // sr [px][ci]

  // stage 0: sr -> LDS bf16 (q's B operand)
  for (int r = 0; r < 16; ++r) {
    int idx = r * 256 + t;
    int ci = idx >> 5, px = idx & 31;
    xT[px][ci] = f2bf(sr[((size_t)b * CC + ci) * HW + px0 + px]);
  }

  // stage 1: conv2 -> mT
  {
    bf16x8 afrag[9][2];
#pragma unroll
    for (int tap = 0; tap < 9; ++tap) {
      const unsigned short* wb =
          wm2t + ((size_t)tap * 128 + w * 32 + col) * 32 + quad * 8;
      afrag[tap][0] = *(const bf16x8*)wb;
      afrag[tap][1] = *(const bf16x8*)(wb + 16 * 32);
    }
    const unsigned short* xb = h1p + (size_t)b * HW * 32;
    f32x4 acc[2][2] = {};
    const bf16x8 zf = {0, 0, 0, 0, 0, 0, 0, 0};
    const int px[2] = {px0 + col, px0 + 16 + col};
    const int xx[2] = {px[0] & 63, px[1] & 63};
    const int yy[2] = {px[0] >> 6, px[1] >> 6};
#pragma unroll
    for (int tap = 0; tap < 9; ++tap) {
      const int dy = tap / 3 - 1, dx = tap % 3 - 1;
      const int shift = dy * 64 + dx;
#pragma unroll
      for (int pt = 0; pt < 2; ++pt) {
        bool valid =
            ((unsigned)(xx[pt] + dx) < 64u) & ((unsigned)(yy[pt] + dy) < 64u);
        bf16x8 bf = *(const bf16x8*)(xb + (size_t)(px[pt] + shift) * 32 + quad * 8);
        bf = valid ? bf : zf;
        acc[0][pt] = mfma16(afrag[tap][0], bf, acc[0][pt]);
        acc[1][pt] = mfma16(afrag[tap][1], bf, acc[1][pt]);
      }
    }
#pragma unroll
    for (int ct = 0; ct < 2; ++ct) {
      float4 bb = *(const float4*)(bm2 + w * 32 + ct * 16 + quad * 4);
#pragma unroll
      for (int pt = 0; pt < 2; ++pt) {
        uint2 pk = {pk2bf_rne(acc[ct][pt][0] + bb.x, acc[ct][pt][1] + bb.y),
                    pk2bf_rne(acc[ct][pt][2] + bb.z, acc[ct][pt][3] + bb.w)};
        *(uint2*)&mT[pt * 16 + col][w * 32 + ct * 16 + quad * 4] = pk;
      }
    }
  }
  __syncthreads();

  // stage 2: q (from xT), k/v (from mT) 1x1 GEMMs
  f32x4 aq[2][2] = {}, ak[2][2] = {}, av[2][2] = {};
  const unsigned short* wqb = wq + (size_t)(w * 32 + col) * CC + quad * 8;
  const unsigned short* wkb = wk + (size_t)(w * 32 + col) * CC + quad * 8;
  const unsigned short* wvb = wv + (size_t)(w * 32 + col) * CC + quad * 8;
#pragma unroll
  for (int ks = 0; ks < 4; ++ks) {
    bf16x8 qa0 = *(const bf16x8*)(wqb + ks * 32);
    bf16x8 qa1 = *(const bf16x8*)(wqb + 16 * CC + ks * 32);
    bf16x8 ka0 = *(const bf16x8*)(wkb + ks * 32);
    bf16x8 ka1 = *(const bf16x8*)(wkb + 16 * CC + ks * 32);
    bf16x8 va0 = *(const bf16x8*)(wvb + ks * 32);
    bf16x8 va1 = *(const bf16x8*)(wvb + 16 * CC + ks * 32);
    bf16x8 bx0 = *(const bf16x8*)&xT[col][ks * 32 + quad * 8];
    bf16x8 bx1 = *(const bf16x8*)&xT[16 + col][ks * 32 + quad * 8];
    bf16x8 bm0 = *(const bf16x8*)&mT[col][ks * 32 + quad * 8];
    bf16x8 bm1f = *(const bf16x8*)&mT[16 + col][ks * 32 + quad * 8];
    aq[0][0] = mfma16(qa0, bx0, aq[0][0]);
    aq[0][1] = mfma16(qa0, bx1, aq[0][1]);
    aq[1][0] = mfma16(qa1, bx0, aq[1][0]);
    aq[1][1] = mfma16(qa1, bx1, aq[1][1]);
    ak[0][0] = mfma16(ka0, bm0, ak[0][0]);
    ak[0][1] = mfma16(ka0, bm1f, ak[0][1]);
    ak[1][0] = mfma16(ka1, bm0, ak[1][0]);
    ak[1][1] = mfma16(ka1, bm1f, ak[1][1]);
    av[0][0] = mfma16(va0, bm0, av[0][0]);
    av[0][1] = mfma16(va0, bm1f, av[0][1]);
    av[1][0] = mfma16(va1, bm0, av[1][0]);
    av[1][1] = mfma16(va1, bm1f, av[1][1]);
  }
  const int bh = b * 4 + w;
  const int chunk = blockIdx.x;
#pragma unroll
  for (int ct = 0; ct < 2; ++ct) {
    float4 bbq = *(const float4*)(bq + w * 32 + ct * 16 + quad * 4);
    float4 bbk = *(const float4*)(bk + w * 32 + ct * 16 + quad * 4);
    float4 bbv = *(const float4*)(bv + w * 32 + ct * 16 + quad * 4);
#pragma unroll
    for (int pt = 0; pt < 2; ++pt) {
      int key = pt * 16 + col;  // pixel within this 32-px chunk
      // q (bias scaled like weights)
      uint2 pkq = {pk2bf_rne(aq[ct][pt][0] + bbq.x * SCALE_LOG2E,
                             aq[ct][pt][1] + bbq.y * SCALE_LOG2E),
                   pk2bf_rne(aq[ct][pt][2] + bbq.z * SCALE_LOG2E,
                             aq[ct][pt][3] + bbq.w * SCALE_LOG2E)};
      *(uint2*)(qt + ((size_t)bh * HW + px0 + key) * 32 + ct * 16 + quad * 4) = pkq;
      // k
      uint2 pkk = {pk2bf_rne(ak[ct][pt][0] + bbk.x, ak[ct][pt][1] + bbk.y),
                   pk2bf_rne(ak[ct][pt][2] + bbk.z, ak[ct][pt][3] + bbk.w)};
      *(uint2*)(kt + ((size_t)bh * HW + px0 + key) * 32 + ct * 16 + quad * 4) = pkk;
      // v: [bh][chunk][dim][key]
      unsigned short* vdst =
          vt + (((size_t)bh * 128 + chunk) * 32 + ct * 16 + quad * 4) * 32 + key;
      vdst[0]  = f2bf(av[ct][pt][0] + bbv.x);
      vdst[32] = f2bf(av[ct][pt][1] + bbv.y);
      vdst[64] = f2bf(av[ct][pt][2] + bbv.z);
      vdst[96] = f2bf(av[ct][pt][3] + bbv.w);
    }
  }
}

// ---------------------------------------------------------------------------
// Split-K flash attention, fixed m=0, 64 queries (4 Q-tiles) per wave,
// 2-stage register pipeline on K/V fragments (c+1 prefetch; benign 2KB
// overread past the split lands in adjacent ws buffers).
// Grid (16, 8, KSPLIT) x 256 threads; each block: 256 queries x 512 keys.
__global__ __launch_bounds__(256, 4) void attn_mfma_kernel(
    const unsigned short* __restrict__ qt, const unsigned short* __restrict__ ktg,
    const unsigned short* __restrict__ vt, unsigned short* __restrict__ opart,
    float* __restrict__ lpart) {
  const int bh   = blockIdx.y;
  const int s    = blockIdx.z;
  const int t    = threadIdx.x;
  const int wave = t >> 6;
  const int lane = t & 63;
  const int col  = lane & 15;
  const int quad = lane >> 4;
  const int q0w  = blockIdx.x * 256 + wave * 64;

  const unsigned short* Qb = qt  + (size_t)bh * HW * 32;
  const unsigned short* Kb = ktg + (size_t)bh * HW * 32;
  const unsigned short* Vc = vt  + (size_t)bh * 128 * 1024;

  __shared__ unsigned short Pt[4][4][16][40];  // [wave][qtile][q][key]

  bf16x8 qf[4];
#pragma unroll
  for (int qt_i = 0; qt_i < 4; ++qt_i)
    qf[qt_i] = *(const bf16x8*)(Qb + (size_t)(q0w + qt_i * 16 + col) * 32 + quad * 8);

  float lacc[4] = {0.f, 0.f, 0.f, 0.f};
  f32x4 o[4][2] = {};
  const f32x4 zero = {0.f, 0.f, 0.f, 0.f};

  const unsigned short* kp1 = Kb + (size_t)(s * 16) * 1024 + col * 32 + quad * 8;
  const unsigned short* kp2 = kp1 + 512;
  const unsigned short* vp1 = Vc + (size_t)(s * 16) * 1024 + col * 32 + quad * 8;
  const unsigned short* vp2 = vp1 + 512;

  bf16x8 kf1 = *(const bf16x8*)(kp1);
  bf16x8 kf2 = *(const bf16x8*)(kp2);
  bf16x8 vf1 = *(const bf16x8*)(vp1);
  bf16x8 vf2 = *(const bf16x8*)(vp2);

  for (int c = 0; c < 16; ++c) {
    // prefetch next chunk (c=15 overreads 2KB into adjacent region, unused)
    bf16x8 nk1 = *(const bf16x8*)(kp1 + (c + 1) * 1024);
    bf16x8 nk2 = *(const bf16x8*)(kp2 + (c + 1) * 1024);
    bf16x8 nv1 = *(const bf16x8*)(vp1 + (c + 1) * 1024);
    bf16x8 nv2 = *(const bf16x8*)(vp2 + (c + 1) * 1024);
#pragma unroll
    for (int qt_i = 0; qt_i < 4; ++qt_i) {
      f32x4 s1 = mfma16(kf1, qf[qt_i], zero);
      f32x4 s2 = mfma16(kf2, qf[qt_i], zero);
      float p0 = __builtin_amdgcn_exp2f(s1[0]);
      float p1 = __builtin_amdgcn_exp2f(s1[1]);
      float p2 = __builtin_amdgcn_exp2f(s1[2]);
      float p3 = __builtin_amdgcn_exp2f(s1[3]);
      float p4 = __builtin_amdgcn_exp2f(s2[0]);
      float p5 = __builtin_amdgcn_exp2f(s2[1]);
      float p6 = __builtin_amdgcn_exp2f(s2[2]);
      float p7 = __builtin_amdgcn_exp2f(s2[3]);
      lacc[qt_i] += ((p0 + p1) + (p2 + p3)) + ((p4 + p5) + (p6 + p7));

      uint2 w1 = {pk2bf(p0, p1), pk2bf(p2, p3)};
      uint2 w2 = {pk2bf(p4, p5), pk2bf(p6, p7)};
      *(uint2*)&Pt[wave][qt_i][col][quad * 4]      = w1;
      *(uint2*)&Pt[wave][qt_i][col][16 + quad * 4] = w2;
      bf16x8 pf = *(const bf16x8*)&Pt[wave][qt_i][col][quad * 8];

      o[qt_i][0] = mfma16(vf1, pf, o[qt_i][0]);
      o[qt_i][1] = mfma16(vf2, pf, o[qt_i][1]);
    }
    kf1 = nk1; kf2 = nk2; vf1 = nv1; vf2 = nv2;
  }

#pragma unroll
  for (int qt_i = 0; qt_i < 4; ++qt_i) {
    float l = lacc[qt_i];
    l += __shfl_xor(l, 16);
    l += __shfl_xor(l, 32);
    int qq = q0w + qt_i * 16 + col;
    size_t base = ((size_t)(s * 8 + bh) * HW + qq) * 32;
    uint2 w1 = {pk2bf_rne(o[qt_i][0][0], o[qt_i][0][1]),
                pk2bf_rne(o[qt_i][0][2], o[qt_i][0][3])};
    uint2 w2 = {pk2bf_rne(o[qt_i][1][0], o[qt_i][1][1]),
                pk2bf_rne(o[qt_i][1][2], o[qt_i][1][3])};
    *(uint2*)(opart + base + quad * 4)      = w1;
    *(uint2*)(opart + base + 16 + quad * 4) = w2;
    if (quad == 0) lpart[(size_t)(s * 8 + bh) * HW + qq] = l;
  }
}

// ---------------------------------------------------------------------------
// Fused combine (KSPLIT partials -> guided, LDS) + output 1x1 conv + bias +
// residual.  Block: 32 px, 256 threads.  Grid (128, 2).
__global__ __launch_bounds__(256) void combine_convo(
    const unsigned short* __restrict__ opart, const float* __restrict__ lpart,
    const unsigned short* __restrict__ wo, const float* __restrict__ bo,
    const float* __restrict__ sr, float* __restrict__ out) {
  const int b   = blockIdx.y;
  const int px0 = blockIdx.x * 32;
  const int t   = threadIdx.x;

  __shared__ unsigned short gT[32][136];  // guided [px][ci]

  // stage 1: combine splits for this block's 32 px into gT
  {
    const int px = t & 31, cs = t >> 5;  // cs 0..7 -> 16-ci slice
    const int q  = px0 + px;
    const int bh = b * 4 + (cs >> 1);
    const int d0 = (cs & 1) * 16;
    float lsum = 0.f;
#pragma unroll
    for (int s = 0; s < KSPLIT; ++s) lsum += lpart[(size_t)(s * 8 + bh) * HW + q];
    float inv = 1.f / lsum;
    float acc[16];
#pragma unroll
    for (int j = 0; j < 16; ++j) acc[j] = 0.f;
#pragma unroll
    for (int s = 0; s < KSPLIT; ++s) {
      const unsigned short* src =
          opart + ((size_t)(s * 8 + bh) * HW + q) * 32 + d0;
#pragma unroll
      for (int g = 0; g < 2; ++g) {
        uint4 raw = *(const uint4*)(src + g * 8);
        const unsigned int* u = (const unsigned int*)&raw;
#pragma unroll
        for (int h = 0; h < 4; ++h) {
          acc[g * 8 + 2 * h]     += __uint_as_float(u[h] << 16);
          acc[g * 8 + 2 * h + 1] += __uint_as_float(u[h] & 0xffff0000u);
        }
      }
    }
    unsigned int pk[8];
#pragma unroll
    for (int j = 0; j < 8; ++j)
      pk[j] = pk2bf_rne(acc[2 * j] * inv, acc[2 * j + 1] * inv);
    *(uint4*)&gT[px][cs * 16]     = *(uint4*)&pk[0];
    *(uint4*)&gT[px][cs * 16 + 8] = *(uint4*)&pk[4];
  }
  __syncthreads();

  // stage 2: 1x1 conv Wo + bias + residual
  const int w = t >> 6, lane = t & 63, col = lane & 15, quad = lane >> 4;
  f32x4 acc2[2][2] = {};
  const unsigned short* wbase = wo + (size_t)(w * 32 + col) * CC + quad * 8;
#pragma unroll
  for (int ks = 0; ks < 4; ++ks) {
    bf16x8 a0 = *(const bf16x8*)(wbase + ks * 32);
    bf16x8 a1 = *(const bf16x8*)(wbase + 16 * CC + ks * 32);
    bf16x8 b0 = *(const bf16x8*)&gT[col][ks * 32 + quad * 8];
    bf16x8 b1 = *(const bf16x8*)&gT[16 + col][ks * 32 + quad * 8];
    acc2[0][0] = mfma16(a0, b0, acc2[0][0]);
    acc2[0][1] = mfma16(a0, b1, acc2[0][1]);
    acc2[1][0] = mfma16(a1, b0, acc2[1][0]);
    acc2[1][1] = mfma16(a1, b1, acc2[1][1]);
  }
#pragma unroll
  for (int ct = 0; ct < 2; ++ct) {
    float4 bb = *(const float4*)(bo + w * 32 + ct * 16 + quad * 4);
    float bias[4] = {bb.x, bb.y, bb.z, bb.w};
#pragma unroll
    for (int pt = 0; pt < 2; ++pt) {
      int px = px0 + pt * 16 + col;
      int co = w * 32 + ct * 16 + quad * 4;
      const float* rb = sr + ((size_t)b * CC + co) * HW + px;
      float* ob = out + ((size_t)b * CC + co) * HW + px;
#pragma unroll
      for (int r = 0; r < 4; ++r)
        ob[(size_t)r * HW] = acc2[ct][pt][r] + bias[r] + rb[(size_t)r * HW];
    }
  }
}

// ---------------------------------------------------------------------------
extern "C" void kernel_launch(void* const* d_in, const int* in_sizes, int n_in,
                              void* d_out, int out_size, void* d_ws, size_t ws_size,
                              hipStream_t stream) {
  const float* sr  = (const float*)d_in[0];
  const float* seg = (const float*)d_in[1];
  const float* Wq  = (const float*)d_in[2];
  const float* bq  = (const float*)d_in[3];
  const float* Wm1 = (const float*)d_in[4];
  const float* bm1 = (const float*)d_in[5];
  const float* Wm2 = (const float*)d_in[6];
  const float* bm2 = (const float*)d_in[7];
  const float* Wk  = (const float*)d_in[8];
  const float* bk  = (const float*)d_in[9];
  const float* Wv  = (const float*)d_in[10];
  const float* bv  = (const float*)d_in[11];
  const float* Wo  = (const float*)d_in[12];
  const float* bo  = (const float*)d_in[13];
  float* out = (float*)d_out;

  unsigned short* h1T = (unsigned short*)d_ws;      // pad + 2*4096*32 + pad
  unsigned short* h1p = h1T + H1PAD;                // usable base
  unsigned short* qt  = h1T + H1PAD + 262144 + H1PAD;
  unsigned short* kt  = qt + 1048576;
  unsigned short* vt  = kt + 1048576;
  unsigned short* wbf = vt + 1048576;               // 4x 1x1 weights bf16
  unsigned short* wm2t = wbf + 65536;               // conv2 weights [tap][co][ci]
  unsigned short* opart = wm2t + 36864;             // 16 MB (KSPLIT=8)
  float* lpart = (float*)(opart + (size_t)KSPLIT * 8 * HW * 32);  // 1 MB

  const unsigned short* wq = wbf;
  const unsigned short* wk = wbf + 16384;
  const unsigned short* wv = wbf + 32768;
  const unsigned short* wo = wbf + 49152;

  prep_kernel<<<432, 256, 0, stream>>>(Wq, Wk, Wv, Wo, Wm2, seg, Wm1, bm1,
                                       wbf, wm2t, h1p);
  conv2qkv_mfma<<<dim3(128, 2), 256, 0, stream>>>(
      sr, h1p, wm2t, bm2, wq, bq, wk, bk, wv, bv, qt, kt, vt);
  attn_mfma_kernel<<<dim3(16, 8, KSPLIT), 256, 0, stream>>>(qt, kt, vt, opart,
                                                            lpart);
  combine_convo<<<dim3(128, 2), 256, 0, stream>>>(opart, lpart, wo, bo, sr, out);
}